// Round 7
// baseline (300.905 us; speedup 1.0000x reference)
//
#include <hip/hip_runtime.h>

typedef __attribute__((ext_vector_type(2))) float f32x2;
typedef unsigned int uintv2 __attribute__((ext_vector_type(2)));

#define N 256
#define BLK 1024
#define SLOTS 290  // stride-9 slots: 9*31+7 = 286 max; 9 coprime 32 => conflict-free

template <int CTRL>
__device__ __forceinline__ float dppmov(float v) {
  return __int_as_float(__builtin_amdgcn_update_dpp(
      0, __float_as_int(v), CTRL, 0xF, 0xF, true));
}

// ---- cross-16 combine within each 32-lane group ----
#if __has_builtin(__builtin_amdgcn_permlane16_swap)
__device__ __forceinline__ float xor16_add(float x) {
  uintv2 r = __builtin_amdgcn_permlane16_swap(__float_as_uint(x),
                                              __float_as_uint(x), false, false);
  return __uint_as_float(r.x) + __uint_as_float(r.y);
}
__device__ __forceinline__ float xor16_max(float x) {
  uintv2 r = __builtin_amdgcn_permlane16_swap(__float_as_uint(x),
                                              __float_as_uint(x), false, false);
  return fmaxf(__uint_as_float(r.x), __uint_as_float(r.y));
}
#else
__device__ __forceinline__ float xor16_add(float x) {
  return x + __int_as_float(
                 __builtin_amdgcn_ds_swizzle(__float_as_int(x), 0x401F));
}
__device__ __forceinline__ float xor16_max(float x) {
  return fmaxf(x, __int_as_float(__builtin_amdgcn_ds_swizzle(
                      __float_as_int(x), 0x401F)));
}
#endif

// ---- cross-32 (half-wave) primitives ----
// pair32: lo <- value lanes 0-31 hold, hi <- value lanes 32-63 hold (uniform).
// swap32_add(a,b): lo lanes return a_lo+a_hi (full-wave combine of a),
//                  hi lanes return b_lo+b_hi. One instruction, two results.
#if __has_builtin(__builtin_amdgcn_permlane32_swap)
__device__ __forceinline__ void pair32(float x, float& lo, float& hi) {
  uintv2 r = __builtin_amdgcn_permlane32_swap(__float_as_uint(x),
                                              __float_as_uint(x), false, false);
  lo = __uint_as_float(r.x);  // [x_lo | x_lo]
  hi = __uint_as_float(r.y);  // [x_hi | x_hi]
}
__device__ __forceinline__ float swap32_add(float a, float b) {
  uintv2 r = __builtin_amdgcn_permlane32_swap(__float_as_uint(a),
                                              __float_as_uint(b), false, false);
  // r.x = [a_lo | b_lo], r.y = [a_hi | b_hi]
  return __uint_as_float(r.x) + __uint_as_float(r.y);
}
__device__ __forceinline__ float swap32_max(float a, float b) {
  uintv2 r = __builtin_amdgcn_permlane32_swap(__float_as_uint(a),
                                              __float_as_uint(b), false, false);
  return fmaxf(__uint_as_float(r.x), __uint_as_float(r.y));
}
#else
__device__ __forceinline__ void pair32(float x, float& lo, float& hi) {
  float o = __shfl_xor(x, 32);
  bool up = (threadIdx.x & 32) != 0;
  lo = up ? o : x;
  hi = up ? x : o;
}
__device__ __forceinline__ float swap32_add(float a, float b) {
  bool up = (threadIdx.x & 32) != 0;
  float mine = up ? b : a;   // my half's target value
  float send = up ? a : b;   // what my partner needs
  return mine + __shfl_xor(send, 32);
}
__device__ __forceinline__ float swap32_max(float a, float b) {
  bool up = (threadIdx.x & 32) != 0;
  float mine = up ? b : a;
  float send = up ? a : b;
  return fmaxf(mine, __shfl_xor(send, 32));
}
#endif

// 32-lane reductions (each half-wave independently; all lanes get result)
__device__ __forceinline__ float rsum32(float v) {
  v += dppmov<0x121>(v);  // row_ror:1
  v += dppmov<0x122>(v);  // row_ror:2
  v += dppmov<0x124>(v);  // row_ror:4
  v += dppmov<0x128>(v);  // row_ror:8
  return xor16_add(v);
}
__device__ __forceinline__ float rmax32(float v) {
  v = fmaxf(v, dppmov<0x121>(v));
  v = fmaxf(v, dppmov<0x122>(v));
  v = fmaxf(v, dppmov<0x124>(v));
  v = fmaxf(v, dppmov<0x128>(v));
  return xor16_max(v);
}
__device__ __forceinline__ f32x2 pkmax(f32x2 a, f32x2 b) {
  f32x2 r;
  r.x = fmaxf(a.x, b.x);
  r.y = fmaxf(a.y, b.y);
  return r;
}

// One probability-domain Sinkhorn iteration (row norm + atomic col partials).
// WR: pre-zeroed accumulator to write; ZR: buffer to zero for iter t+1
// (its readers finished >=1 barrier ago -> race-free). One barrier total.
__device__ __forceinline__ void prob_iter(f32x2 (&p)[8][4], f32x2 (&Vr)[4],
                                          float* WR, float* ZR, int slot,
                                          int hi) {
  f32x2 ps[4];
  ps[0] = ps[1] = ps[2] = ps[3] = (f32x2){0.f, 0.f};
  #pragma unroll
  for (int r = 0; r < 8; ++r) {
    p[r][0] *= Vr[0]; p[r][1] *= Vr[1];
    p[r][2] *= Vr[2]; p[r][3] *= Vr[3];
    f32x2 t2 = (p[r][0] + p[r][1]) + (p[r][2] + p[r][3]);
    float g = __builtin_amdgcn_rcpf(rsum32(t2.x + t2.y));
    p[r][0] *= g; p[r][1] *= g; p[r][2] *= g; p[r][3] *= g;
    ps[0] += p[r][0]; ps[1] += p[r][1];
    ps[2] += p[r][2]; ps[3] += p[r][3];
  }
  const float psf[8] = {ps[0].x, ps[0].y, ps[1].x, ps[1].y,
                        ps[2].x, ps[2].y, ps[3].x, ps[3].y};
  // Full-wave combine: lo lanes get col j (j=0..3), hi lanes col j+4 —
  // matching slot = 9*cg + hi*4. Each slot then receives 16 atomics (1/wave).
  #pragma unroll
  for (int j = 0; j < 4; ++j)
    atomicAdd(&WR[slot + j], swap32_add(psf[j], psf[j + 4]));
  #pragma unroll
  for (int j = 0; j < 4; ++j) ZR[slot + j] = 0.f;
  __syncthreads();
  float vf[8];
  #pragma unroll
  for (int j = 0; j < 4; ++j) {
    float s = __builtin_amdgcn_rcpf(WR[slot + j]);
    pair32(s, vf[j], vf[j + 4]);
  }
  Vr[0] = (f32x2){vf[0], vf[1]};
  Vr[1] = (f32x2){vf[2], vf[3]};
  Vr[2] = (f32x2){vf[4], vf[5]};
  Vr[3] = (f32x2){vf[6], vf[7]};
}

// One block = one 256x256 matrix, 16 waves.
// Thread (rg = tid>>5, cg = tid&31) owns rows rg*8..+7, cols cg*8..+7.
// Iteration 0: stabilized log2 domain (atomicMin on f32 bits for col max —
// valid since all entries <= 0 post row-norm). Iterations 1..20: probability
// domain, one barrier each, triple-buffered atomic col sums.
__global__ __launch_bounds__(BLK, 2)
void sinkhorn_kernel(const float* __restrict__ x, float* __restrict__ out) {
  __shared__ float S0[SLOTS], S1[SLOTS], S2[SLOTS];

  const int tid = threadIdx.x;
  const int cg = tid & 31;
  const int rg = tid >> 5;
  const int r0 = rg * 8;
  const int hi = rg & 1;               // upper half of its wave
  const int slot = 9 * cg + hi * 4;    // 4 slots per half-wave lane
  const long mat = blockIdx.x;
  const float SCALE = 144.2695040888963407f;  // log2(e)/0.01

  if (tid < SLOTS) {
    S0[tid] = 0.f;
    S1[tid] = 0.f;
    reinterpret_cast<unsigned*>(S2)[tid] = 0xFFFFFFFFu;  // +max for uint-min
  }

  const float4* __restrict__ src4 =
      reinterpret_cast<const float4*>(x + mat * (long)(N * N));
  f32x2 p[8][4];
  #pragma unroll
  for (int r = 0; r < 8; ++r) {
    float4 a = src4[(r0 + r) * 64 + cg * 2];
    float4 b = src4[(r0 + r) * 64 + cg * 2 + 1];
    f32x2 t;
    t.x = a.x; t.y = a.y; p[r][0] = t * SCALE;
    t.x = a.z; t.y = a.w; p[r][1] = t * SCALE;
    t.x = b.x; t.y = b.y; p[r][2] = t * SCALE;
    t.x = b.z; t.y = b.w; p[r][3] = t * SCALE;
  }

  // ========== iteration 0: log2 domain, stabilized ==========
  #pragma unroll
  for (int r = 0; r < 8; ++r) {
    f32x2 m2 = pkmax(pkmax(p[r][0], p[r][1]), pkmax(p[r][2], p[r][3]));
    float m = rmax32(fmaxf(m2.x, m2.y));
    float s = 0.f;
    #pragma unroll
    for (int j = 0; j < 4; ++j) {
      s += __builtin_amdgcn_exp2f(p[r][j].x - m);
      s += __builtin_amdgcn_exp2f(p[r][j].y - m);
    }
    s = rsum32(s);
    float L = m + __builtin_amdgcn_logf(s);  // v_log_f32 = log2
    #pragma unroll
    for (int j = 0; j < 4; ++j) p[r][j] -= L;
  }
  __syncthreads();  // orders the S0/S1/S2 init before any atomic

  // col max via atomicMin on raw bits (all values <= 0: float max == uint min)
  {
    f32x2 cm[4];
    #pragma unroll
    for (int j = 0; j < 4; ++j) cm[j] = p[0][j];
    #pragma unroll
    for (int r = 1; r < 8; ++r) {
      #pragma unroll
      for (int j = 0; j < 4; ++j) cm[j] = pkmax(cm[j], p[r][j]);
    }
    const float cmf[8] = {cm[0].x, cm[0].y, cm[1].x, cm[1].y,
                          cm[2].x, cm[2].y, cm[3].x, cm[3].y};
    unsigned* S2u = reinterpret_cast<unsigned*>(S2);
    #pragma unroll
    for (int j = 0; j < 4; ++j)
      atomicMin(&S2u[slot + j],
                __float_as_uint(swap32_max(cmf[j], cmf[j + 4])));
    __syncthreads();
    float Mf[8];
    #pragma unroll
    for (int j = 0; j < 4; ++j) {
      float xx = __uint_as_float(S2u[slot + j]);
      pair32(xx, Mf[j], Mf[j + 4]);
    }
    // exp sweep -> probability domain; accumulate col-sum partials
    f32x2 ps[4];
    ps[0] = ps[1] = ps[2] = ps[3] = (f32x2){0.f, 0.f};
    #pragma unroll
    for (int r = 0; r < 8; ++r) {
      #pragma unroll
      for (int k = 0; k < 4; ++k) {
        f32x2 v;
        v.x = __builtin_amdgcn_exp2f(p[r][k].x - Mf[2 * k]);
        v.y = __builtin_amdgcn_exp2f(p[r][k].y - Mf[2 * k + 1]);
        p[r][k] = v;
        ps[k] += v;
      }
    }
    const float psf[8] = {ps[0].x, ps[0].y, ps[1].x, ps[1].y,
                          ps[2].x, ps[2].y, ps[3].x, ps[3].y};
    #pragma unroll
    for (int j = 0; j < 4; ++j)
      atomicAdd(&S0[slot + j], swap32_add(psf[j], psf[j + 4]));
    __syncthreads();
  }
  f32x2 Vr[4];
  {
    float vf[8];
    #pragma unroll
    for (int j = 0; j < 4; ++j) {
      float s = __builtin_amdgcn_rcpf(S0[slot + j]);
      pair32(s, vf[j], vf[j + 4]);
    }
    Vr[0] = (f32x2){vf[0], vf[1]};
    Vr[1] = (f32x2){vf[2], vf[3]};
    Vr[2] = (f32x2){vf[4], vf[5]};
    Vr[3] = (f32x2){vf[6], vf[7]};
  }

  // ========== iterations 1..20: probability domain ==========
  // t: WR = buf[t%3], ZR = buf[(t+1)%3]  (A=S0,B=S1,C=S2)
  #pragma unroll 1
  for (int u = 0; u < 6; ++u) {
    prob_iter(p, Vr, S1, S2, slot, hi);  // t = 3u+1
    prob_iter(p, Vr, S2, S0, slot, hi);  // t = 3u+2
    prob_iter(p, Vr, S0, S1, slot, hi);  // t = 3u+3
  }
  prob_iter(p, Vr, S1, S2, slot, hi);    // t = 19
  prob_iter(p, Vr, S2, S0, slot, hi);    // t = 20

  // ---- final lazy col-normalize + store ----
  float4* __restrict__ dst4 =
      reinterpret_cast<float4*>(out + mat * (long)(N * N));
  #pragma unroll
  for (int r = 0; r < 8; ++r) {
    f32x2 a = p[r][0] * Vr[0];
    f32x2 b = p[r][1] * Vr[1];
    f32x2 c = p[r][2] * Vr[2];
    f32x2 d = p[r][3] * Vr[3];
    dst4[(r0 + r) * 64 + cg * 2] = make_float4(a.x, a.y, b.x, b.y);
    dst4[(r0 + r) * 64 + cg * 2 + 1] = make_float4(c.x, c.y, d.x, d.y);
  }
}

extern "C" void kernel_launch(void* const* d_in, const int* in_sizes, int n_in,
                              void* d_out, int out_size, void* d_ws, size_t ws_size,
                              hipStream_t stream) {
  const float* x = (const float*)d_in[0];
  float* out = (float*)d_out;
  int B = in_sizes[0] / (N * N);
  hipLaunchKernelGGL(sinkhorn_kernel, dim3(B), dim3(BLK), 0, stream, x, out);
}

// Round 11
// 173.595 us; speedup vs baseline: 1.7334x; 1.7334x over previous
//
#include <hip/hip_runtime.h>

typedef unsigned int uintv2 __attribute__((ext_vector_type(2)));

#define N 256
#define BLK 1024
#define NWAVE 16
#define SCALE 144.2695040888963407f  // log2(e)/0.01
#define TSTRIDE 288                  // 32 slots * 9 floats (9 coprime 32 -> conflict-free)

template <int CTRL>
__device__ __forceinline__ float dppf(float v) {
  return __int_as_float(__builtin_amdgcn_update_dpp(
      0, __float_as_int(v), CTRL, 0xF, 0xF, true));
}

#if __has_builtin(__builtin_amdgcn_permlane16_swap)
__device__ __forceinline__ float xor16_add(float x) {
  uintv2 r = __builtin_amdgcn_permlane16_swap(__float_as_uint(x),
                                              __float_as_uint(x), false, false);
  return __uint_as_float(r.x) + __uint_as_float(r.y);
}
__device__ __forceinline__ float xor16_max(float x) {
  uintv2 r = __builtin_amdgcn_permlane16_swap(__float_as_uint(x),
                                              __float_as_uint(x), false, false);
  return fmaxf(__uint_as_float(r.x), __uint_as_float(r.y));
}
#else
__device__ __forceinline__ float xor16_add(float x) {
  return x + __int_as_float(__builtin_amdgcn_ds_swizzle(__float_as_int(x), 0x401F));
}
__device__ __forceinline__ float xor16_max(float x) {
  return fmaxf(x, __int_as_float(__builtin_amdgcn_ds_swizzle(__float_as_int(x), 0x401F)));
}
#endif

#if __has_builtin(__builtin_amdgcn_permlane32_swap)
__device__ __forceinline__ float swap32_add(float a) {
  uintv2 r = __builtin_amdgcn_permlane32_swap(__float_as_uint(a),
                                              __float_as_uint(a), false, false);
  return __uint_as_float(r.x) + __uint_as_float(r.y);
}
__device__ __forceinline__ float swap32_max(float a) {
  uintv2 r = __builtin_amdgcn_permlane32_swap(__float_as_uint(a),
                                              __float_as_uint(a), false, false);
  return fmaxf(__uint_as_float(r.x), __uint_as_float(r.y));
}
#else
__device__ __forceinline__ float swap32_add(float a) { return a + __shfl_xor(a, 32); }
__device__ __forceinline__ float swap32_max(float a) { return fmaxf(a, __shfl_xor(a, 32)); }
#endif

__device__ __forceinline__ float rsum32(float v) {
  v += dppf<0x121>(v);
  v += dppf<0x122>(v);
  v += dppf<0x124>(v);
  v += dppf<0x128>(v);
  return xor16_add(v);
}
__device__ __forceinline__ float rmax32(float v) {
  v = fmaxf(v, dppf<0x121>(v));
  v = fmaxf(v, dppf<0x122>(v));
  v = fmaxf(v, dppf<0x124>(v));
  v = fmaxf(v, dppf<0x128>(v));
  return xor16_max(v);
}

// Pack two f32 into a bf16 pair (RNE). bf16 keeps f32's exponent range —
// essential: f16's 2^-24 flush destroyed conflict-column entries (Round 10).
__device__ __forceinline__ unsigned bfpack(float lo, float hi) {
  unsigned ul = __float_as_uint(lo);
  unsigned uh = __float_as_uint(hi);
  ul = (ul + 0x7FFFu + ((ul >> 16) & 1u)) >> 16;
  uh = (uh + 0x7FFFu + ((uh >> 16) & 1u)) & 0xFFFF0000u;
  return uh | ul;
}
__device__ __forceinline__ float bflo(unsigned u) {
  return __uint_as_float(u << 16);
}
__device__ __forceinline__ float bfhi(unsigned u) {
  return __uint_as_float(u & 0xFFFF0000u);
}

// One block = one 256x256 matrix, 16 waves.
// Thread (rg=tid>>5, cg=tid&31) owns rows rg*8..+7, cols cg*8..+7.
// Dual-scaling Sinkhorn: P = b * R_i * C_j with b STATIC in packed bf16
// (b = 2^(q - K'), q = t - M_j, K' = row max of q; row max = col max = 1;
// bf16 exponent = f32's, so the flush behavior matches the f32 kernels that
// passed in rounds 3-5). All R/C/tree math f32; clamped rcp (no NaN path).
// C1 = rcp(sum_i b * 2^{K'_i - L_i}) matches the reference's first col-norm.
__global__ __launch_bounds__(BLK, 2)
void sinkhorn_kernel(const float* __restrict__ x, float* __restrict__ out) {
  __shared__ float ldsT[NWAVE * TSTRIDE];  // reduction tree partials (f32)
  __shared__ float ldsCf[N];               // f32 C per col
  __shared__ float ldsL[N];                // row lse (iter0)
  __shared__ float ldsM[N];                // col max (iter0)

  const int tid = threadIdx.x;
  const int cg = tid & 31;
  const int rg = tid >> 5;
  const int w = tid >> 6;
  const int r0 = rg * 8;
  const int tbase = w * TSTRIDE + cg * 9;  // this lane's tree slot base
  const long mat = blockIdx.x;

  const float4* __restrict__ src4 =
      reinterpret_cast<const float4*>(x + mat * (long)(N * N));

  // ---------- phase A: row lse (log2 domain) -> ldsL ----------
  #pragma unroll
  for (int r = 0; r < 8; ++r) {
    float4 a = src4[(r0 + r) * 64 + cg * 2];
    float4 bq = src4[(r0 + r) * 64 + cg * 2 + 1];
    float m = fmaxf(fmaxf(fmaxf(a.x, a.y), fmaxf(a.z, a.w)),
                    fmaxf(fmaxf(bq.x, bq.y), fmaxf(bq.z, bq.w)));
    m = rmax32(m) * SCALE;  // max(x)*SCALE == max(x*SCALE), SCALE>0
    float s = __builtin_amdgcn_exp2f(fmaf(a.x, SCALE, -m)) +
              __builtin_amdgcn_exp2f(fmaf(a.y, SCALE, -m)) +
              __builtin_amdgcn_exp2f(fmaf(a.z, SCALE, -m)) +
              __builtin_amdgcn_exp2f(fmaf(a.w, SCALE, -m)) +
              __builtin_amdgcn_exp2f(fmaf(bq.x, SCALE, -m)) +
              __builtin_amdgcn_exp2f(fmaf(bq.y, SCALE, -m)) +
              __builtin_amdgcn_exp2f(fmaf(bq.z, SCALE, -m)) +
              __builtin_amdgcn_exp2f(fmaf(bq.w, SCALE, -m));
    s = rsum32(s);
    if (cg == 0) ldsL[r0 + r] = m + __builtin_amdgcn_logf(s);  // v_log = log2
  }
  __syncthreads();

  // ---------- phase B: col max of (t - L) -> ldsM ----------
  {
    float cm[8];
    #pragma unroll
    for (int k = 0; k < 8; ++k) cm[k] = -3.0e38f;
    #pragma unroll
    for (int r = 0; r < 8; ++r) {
      float Lr = ldsL[r0 + r];
      float4 a = src4[(r0 + r) * 64 + cg * 2];
      float4 bq = src4[(r0 + r) * 64 + cg * 2 + 1];
      cm[0] = fmaxf(cm[0], fmaf(a.x, SCALE, -Lr));
      cm[1] = fmaxf(cm[1], fmaf(a.y, SCALE, -Lr));
      cm[2] = fmaxf(cm[2], fmaf(a.z, SCALE, -Lr));
      cm[3] = fmaxf(cm[3], fmaf(a.w, SCALE, -Lr));
      cm[4] = fmaxf(cm[4], fmaf(bq.x, SCALE, -Lr));
      cm[5] = fmaxf(cm[5], fmaf(bq.y, SCALE, -Lr));
      cm[6] = fmaxf(cm[6], fmaf(bq.z, SCALE, -Lr));
      cm[7] = fmaxf(cm[7], fmaf(bq.w, SCALE, -Lr));
    }
    #pragma unroll
    for (int k = 0; k < 8; ++k) cm[k] = swap32_max(cm[k]);
    if (tid & 32) {
      ldsT[tbase + 4] = cm[4]; ldsT[tbase + 5] = cm[5];
      ldsT[tbase + 6] = cm[6]; ldsT[tbase + 7] = cm[7];
    } else {
      ldsT[tbase + 0] = cm[0]; ldsT[tbase + 1] = cm[1];
      ldsT[tbase + 2] = cm[2]; ldsT[tbase + 3] = cm[3];
    }
  }
  __syncthreads();
  {
    const int col = tid >> 2, q4 = tid & 3;
    const int slot = (col >> 3) * 9 + (col & 7);
    float M = fmaxf(fmaxf(ldsT[(q4 * 4 + 0) * TSTRIDE + slot],
                          ldsT[(q4 * 4 + 1) * TSTRIDE + slot]),
                    fmaxf(ldsT[(q4 * 4 + 2) * TSTRIDE + slot],
                          ldsT[(q4 * 4 + 3) * TSTRIDE + slot]));
    M = fmaxf(M, dppf<0xB1>(M));
    M = fmaxf(M, dppf<0x4E>(M));
    if (q4 == 0) ldsM[col] = M;
  }
  __syncthreads();

  // ---------- phase C: b = 2^(q - K') -> bf16; G_j = sum_i b*2^{K'-L} ----------
  unsigned bp[8][4];  // packed bf16 pairs, 32 VGPRs of matrix data
  {
    const float4* m4 = reinterpret_cast<const float4*>(ldsM);
    float4 mA = m4[cg * 2], mB = m4[cg * 2 + 1];
    float cs[8];
    #pragma unroll
    for (int k = 0; k < 8; ++k) cs[k] = 0.f;
    #pragma unroll
    for (int r = 0; r < 8; ++r) {
      float Lr = ldsL[r0 + r];
      float4 a = src4[(r0 + r) * 64 + cg * 2];
      float4 bq = src4[(r0 + r) * 64 + cg * 2 + 1];
      float q0 = fmaf(a.x, SCALE, -mA.x), q1 = fmaf(a.y, SCALE, -mA.y);
      float q2 = fmaf(a.z, SCALE, -mA.z), q3 = fmaf(a.w, SCALE, -mA.w);
      float q4v = fmaf(bq.x, SCALE, -mB.x), q5 = fmaf(bq.y, SCALE, -mB.y);
      float q6 = fmaf(bq.z, SCALE, -mB.z), q7 = fmaf(bq.w, SCALE, -mB.w);
      float Kp = fmaxf(fmaxf(fmaxf(q0, q1), fmaxf(q2, q3)),
                       fmaxf(fmaxf(q4v, q5), fmaxf(q6, q7)));
      Kp = rmax32(Kp);                             // row max of q
      float eK = __builtin_amdgcn_exp2f(Kp - Lr);  // 2^{K'_i - L_i} <= ~1
      float e0 = __builtin_amdgcn_exp2f(q0 - Kp), e1 = __builtin_amdgcn_exp2f(q1 - Kp);
      float e2 = __builtin_amdgcn_exp2f(q2 - Kp), e3 = __builtin_amdgcn_exp2f(q3 - Kp);
      float e4 = __builtin_amdgcn_exp2f(q4v - Kp), e5 = __builtin_amdgcn_exp2f(q5 - Kp);
      float e6 = __builtin_amdgcn_exp2f(q6 - Kp), e7 = __builtin_amdgcn_exp2f(q7 - Kp);
      bp[r][0] = bfpack(e0, e1); bp[r][1] = bfpack(e2, e3);
      bp[r][2] = bfpack(e4, e5); bp[r][3] = bfpack(e6, e7);
      cs[0] = fmaf(e0, eK, cs[0]); cs[1] = fmaf(e1, eK, cs[1]);
      cs[2] = fmaf(e2, eK, cs[2]); cs[3] = fmaf(e3, eK, cs[3]);
      cs[4] = fmaf(e4, eK, cs[4]); cs[5] = fmaf(e5, eK, cs[5]);
      cs[6] = fmaf(e6, eK, cs[6]); cs[7] = fmaf(e7, eK, cs[7]);
    }
    #pragma unroll
    for (int k = 0; k < 8; ++k) cs[k] = swap32_add(cs[k]);
    if (tid & 32) {
      ldsT[tbase + 4] = cs[4]; ldsT[tbase + 5] = cs[5];
      ldsT[tbase + 6] = cs[6]; ldsT[tbase + 7] = cs[7];
    } else {
      ldsT[tbase + 0] = cs[0]; ldsT[tbase + 1] = cs[1];
      ldsT[tbase + 2] = cs[2]; ldsT[tbase + 3] = cs[3];
    }
  }
  __syncthreads();
  {
    const int col = tid >> 2, q4 = tid & 3;
    const int slot = (col >> 3) * 9 + (col & 7);
    float S = ldsT[(q4 * 4 + 0) * TSTRIDE + slot] +
              ldsT[(q4 * 4 + 1) * TSTRIDE + slot] +
              ldsT[(q4 * 4 + 2) * TSTRIDE + slot] +
              ldsT[(q4 * 4 + 3) * TSTRIDE + slot];
    S += dppf<0xB1>(S);
    S += dppf<0x4E>(S);
    if (q4 == 0) ldsCf[col] = __builtin_amdgcn_rcpf(fmaxf(S, 1e-30f));
  }
  __syncthreads();

  float Cf[8];
  {
    const float4* cf4 = reinterpret_cast<const float4*>(ldsCf);
    float4 cA = cf4[cg * 2], cB = cf4[cg * 2 + 1];
    Cf[0] = cA.x; Cf[1] = cA.y; Cf[2] = cA.z; Cf[3] = cA.w;
    Cf[4] = cB.x; Cf[5] = cB.y; Cf[6] = cB.z; Cf[7] = cB.w;
  }

  // ---------- iterations 2..20 (19x): R temp, C update; all f32 ----------
  #pragma unroll 1
  for (int it = 0; it < 19; ++it) {
    float ps[8];
    #pragma unroll
    for (int k = 0; k < 8; ++k) ps[k] = 0.f;
    #pragma unroll
    for (int r = 0; r < 8; ++r) {
      float bu[8];
      #pragma unroll
      for (int k = 0; k < 4; ++k) {
        unsigned u = bp[r][k];
        bu[2 * k] = bflo(u);
        bu[2 * k + 1] = bfhi(u);
      }
      float s = 0.f;
      #pragma unroll
      for (int k = 0; k < 8; ++k) s = fmaf(bu[k], Cf[k], s);
      s = rsum32(s);
      float Rr = __builtin_amdgcn_rcpf(fmaxf(s, 1e-30f));
      #pragma unroll
      for (int k = 0; k < 8; ++k) ps[k] = fmaf(bu[k], Rr, ps[k]);
    }
    #pragma unroll
    for (int k = 0; k < 8; ++k) ps[k] = swap32_add(ps[k]);
    if (tid & 32) {
      ldsT[tbase + 4] = ps[4]; ldsT[tbase + 5] = ps[5];
      ldsT[tbase + 6] = ps[6]; ldsT[tbase + 7] = ps[7];
    } else {
      ldsT[tbase + 0] = ps[0]; ldsT[tbase + 1] = ps[1];
      ldsT[tbase + 2] = ps[2]; ldsT[tbase + 3] = ps[3];
    }
    __syncthreads();
    {
      const int col = tid >> 2, q4 = tid & 3;
      const int slot = (col >> 3) * 9 + (col & 7);
      float S = ldsT[(q4 * 4 + 0) * TSTRIDE + slot] +
                ldsT[(q4 * 4 + 1) * TSTRIDE + slot] +
                ldsT[(q4 * 4 + 2) * TSTRIDE + slot] +
                ldsT[(q4 * 4 + 3) * TSTRIDE + slot];
      S += dppf<0xB1>(S);
      S += dppf<0x4E>(S);
      if (q4 == 0) ldsCf[col] = __builtin_amdgcn_rcpf(fmaxf(S, 1e-30f));
    }
    __syncthreads();
    {
      const float4* cf4 = reinterpret_cast<const float4*>(ldsCf);
      float4 cA = cf4[cg * 2], cB = cf4[cg * 2 + 1];
      Cf[0] = cA.x; Cf[1] = cA.y; Cf[2] = cA.z; Cf[3] = cA.w;
      Cf[4] = cB.x; Cf[5] = cB.y; Cf[6] = cB.z; Cf[7] = cB.w;
    }
  }

  // ---------- peeled iteration 21: keep R, final C ----------
  float R[8];
  {
    float ps[8];
    #pragma unroll
    for (int k = 0; k < 8; ++k) ps[k] = 0.f;
    #pragma unroll
    for (int r = 0; r < 8; ++r) {
      float bu[8];
      #pragma unroll
      for (int k = 0; k < 4; ++k) {
        unsigned u = bp[r][k];
        bu[2 * k] = bflo(u);
        bu[2 * k + 1] = bfhi(u);
      }
      float s = 0.f;
      #pragma unroll
      for (int k = 0; k < 8; ++k) s = fmaf(bu[k], Cf[k], s);
      s = rsum32(s);
      float Rr = __builtin_amdgcn_rcpf(fmaxf(s, 1e-30f));
      R[r] = Rr;
      #pragma unroll
      for (int k = 0; k < 8; ++k) ps[k] = fmaf(bu[k], Rr, ps[k]);
    }
    #pragma unroll
    for (int k = 0; k < 8; ++k) ps[k] = swap32_add(ps[k]);
    if (tid & 32) {
      ldsT[tbase + 4] = ps[4]; ldsT[tbase + 5] = ps[5];
      ldsT[tbase + 6] = ps[6]; ldsT[tbase + 7] = ps[7];
    } else {
      ldsT[tbase + 0] = ps[0]; ldsT[tbase + 1] = ps[1];
      ldsT[tbase + 2] = ps[2]; ldsT[tbase + 3] = ps[3];
    }
    __syncthreads();
    {
      const int col = tid >> 2, q4 = tid & 3;
      const int slot = (col >> 3) * 9 + (col & 7);
      float S = ldsT[(q4 * 4 + 0) * TSTRIDE + slot] +
                ldsT[(q4 * 4 + 1) * TSTRIDE + slot] +
                ldsT[(q4 * 4 + 2) * TSTRIDE + slot] +
                ldsT[(q4 * 4 + 3) * TSTRIDE + slot];
      S += dppf<0xB1>(S);
      S += dppf<0x4E>(S);
      if (q4 == 0) ldsCf[col] = __builtin_amdgcn_rcpf(fmaxf(S, 1e-30f));
    }
    __syncthreads();
  }

  // ---------- output: P = b * R_i * C_j (f32) ----------
  float4* __restrict__ dst4 =
      reinterpret_cast<float4*>(out + mat * (long)(N * N));
  const float4* cf4 = reinterpret_cast<const float4*>(ldsCf);
  float4 cA = cf4[cg * 2], cB = cf4[cg * 2 + 1];
  #pragma unroll
  for (int r = 0; r < 8; ++r) {
    float Rr = R[r];
    float4 o0, o1;
    o0.x = bflo(bp[r][0]) * Rr * cA.x;
    o0.y = bfhi(bp[r][0]) * Rr * cA.y;
    o0.z = bflo(bp[r][1]) * Rr * cA.z;
    o0.w = bfhi(bp[r][1]) * Rr * cA.w;
    o1.x = bflo(bp[r][2]) * Rr * cB.x;
    o1.y = bfhi(bp[r][2]) * Rr * cB.y;
    o1.z = bflo(bp[r][3]) * Rr * cB.z;
    o1.w = bfhi(bp[r][3]) * Rr * cB.w;
    dst4[(r0 + r) * 64 + cg * 2] = o0;
    dst4[(r0 + r) * 64 + cg * 2 + 1] = o1;
  }
}

extern "C" void kernel_launch(void* const* d_in, const int* in_sizes, int n_in,
                              void* d_out, int out_size, void* d_ws, size_t ws_size,
                              hipStream_t stream) {
  const float* x = (const float*)d_in[0];
  float* out = (float*)d_out;
  int B = in_sizes[0] / (N * N);
  hipLaunchKernelGGL(sinkhorn_kernel, dim3(B), dim3(BLK), 0, stream, x, out);
}

// Round 12
// 126.801 us; speedup vs baseline: 2.3731x; 1.3690x over previous
//
#include <hip/hip_runtime.h>

typedef __attribute__((ext_vector_type(2))) float f32x2;
typedef unsigned int uintv2 __attribute__((ext_vector_type(2)));

#define N 256
#define BLK 1024
#define NWAVE 16
#define SCALE 144.2695040888963407f  // log2(e)/0.01
#define TSTRIDE 352                  // ≡ 0 mod 32; room for slot(<=286) + 4w(<=60)

template <int CTRL>
__device__ __forceinline__ float dppf(float v) {
  return __int_as_float(__builtin_amdgcn_update_dpp(
      0, __float_as_int(v), CTRL, 0xF, 0xF, true));
}

#if __has_builtin(__builtin_amdgcn_permlane16_swap)
__device__ __forceinline__ float xor16_add(float x) {
  uintv2 r = __builtin_amdgcn_permlane16_swap(__float_as_uint(x),
                                              __float_as_uint(x), false, false);
  return __uint_as_float(r.x) + __uint_as_float(r.y);
}
__device__ __forceinline__ float xor16_max(float x) {
  uintv2 r = __builtin_amdgcn_permlane16_swap(__float_as_uint(x),
                                              __float_as_uint(x), false, false);
  return fmaxf(__uint_as_float(r.x), __uint_as_float(r.y));
}
#else
__device__ __forceinline__ float xor16_add(float x) {
  return x + __int_as_float(__builtin_amdgcn_ds_swizzle(__float_as_int(x), 0x401F));
}
__device__ __forceinline__ float xor16_max(float x) {
  return fmaxf(x, __int_as_float(__builtin_amdgcn_ds_swizzle(__float_as_int(x), 0x401F)));
}
#endif

#if __has_builtin(__builtin_amdgcn_permlane32_swap)
__device__ __forceinline__ float swap32_add(float a) {
  uintv2 r = __builtin_amdgcn_permlane32_swap(__float_as_uint(a),
                                              __float_as_uint(a), false, false);
  return __uint_as_float(r.x) + __uint_as_float(r.y);
}
__device__ __forceinline__ float swap32_max(float a) {
  uintv2 r = __builtin_amdgcn_permlane32_swap(__float_as_uint(a),
                                              __float_as_uint(a), false, false);
  return fmaxf(__uint_as_float(r.x), __uint_as_float(r.y));
}
#else
__device__ __forceinline__ float swap32_add(float a) { return a + __shfl_xor(a, 32); }
__device__ __forceinline__ float swap32_max(float a) { return fmaxf(a, __shfl_xor(a, 32)); }
#endif

__device__ __forceinline__ float rsum32(float v) {
  v += dppf<0x121>(v);
  v += dppf<0x122>(v);
  v += dppf<0x124>(v);
  v += dppf<0x128>(v);
  return xor16_add(v);
}
__device__ __forceinline__ float rmax32(float v) {
  v = fmaxf(v, dppf<0x121>(v));
  v = fmaxf(v, dppf<0x122>(v));
  v = fmaxf(v, dppf<0x124>(v));
  v = fmaxf(v, dppf<0x128>(v));
  return xor16_max(v);
}
__device__ __forceinline__ f32x2 pkmax(f32x2 a, f32x2 b) {
  f32x2 r;
  r.x = fmaxf(a.x, b.x);
  r.y = fmaxf(a.y, b.y);
  return r;
}

// One block = one 256x256 matrix, 16 waves.
// Thread (rg=tid>>5, cg=tid&31) owns rows rg*8..+7, cols cg*8..+7.
// Dual-scaling Sinkhorn: P = b * R_i * C_j with b STATIC in f32x2 registers
// (b = 2^(u - M_j - K_i), u = t - rowlse(t), M = colmax(u), K = rowmax(u-M));
// input read from global exactly ONCE; all init phases in-register.
// Per iteration (packed math): R_i = rcp(sum_j b*C); C_j = rcp(sum_i b*R).
// LDS tree: slot = 9*(col/8)+(col&7), rotated +4*wave -> ~2-way banks only.
// Trajectory identical to Round 11's verified kernel; b in f32 (more accurate).
__global__ __launch_bounds__(BLK, 2)
void sinkhorn_kernel(const float* __restrict__ x, float* __restrict__ out) {
  __shared__ float ldsT[NWAVE * TSTRIDE];  // tree partials, rotated layout
  __shared__ float ldsM[N];                // col max (init)
  __shared__ float ldsCf[N];               // f32 C per col

  const int tid = threadIdx.x;
  const int cg = tid & 31;
  const int rg = tid >> 5;
  const int w = tid >> 6;
  const int r0 = rg * 8;
  const int wbase = w * TSTRIDE + cg * 9 + 4 * w;  // this lane's write base
  const long mat = blockIdx.x;

  // ---------- load once: b = x * SCALE (f32x2[8][4]) ----------
  const float4* __restrict__ src4 =
      reinterpret_cast<const float4*>(x + mat * (long)(N * N));
  f32x2 b[8][4];
  #pragma unroll
  for (int r = 0; r < 8; ++r) {
    float4 a = src4[(r0 + r) * 64 + cg * 2];
    float4 bq = src4[(r0 + r) * 64 + cg * 2 + 1];
    b[r][0] = (f32x2){a.x, a.y} * SCALE;
    b[r][1] = (f32x2){a.z, a.w} * SCALE;
    b[r][2] = (f32x2){bq.x, bq.y} * SCALE;
    b[r][3] = (f32x2){bq.z, bq.w} * SCALE;
  }

  // ---------- phase A: u = t - rowlse(t), in-register ----------
  #pragma unroll
  for (int r = 0; r < 8; ++r) {
    f32x2 m2 = pkmax(pkmax(b[r][0], b[r][1]), pkmax(b[r][2], b[r][3]));
    float m = rmax32(fmaxf(m2.x, m2.y));
    float s = 0.f;
    #pragma unroll
    for (int j = 0; j < 4; ++j) {
      s += __builtin_amdgcn_exp2f(b[r][j].x - m);
      s += __builtin_amdgcn_exp2f(b[r][j].y - m);
    }
    s = rsum32(s);
    float L = m + __builtin_amdgcn_logf(s);  // v_log_f32 = log2
    #pragma unroll
    for (int j = 0; j < 4; ++j) b[r][j] -= (f32x2){L, L};
  }

  // ---------- phase B: M_j = colmax(u) via tree ----------
  {
    f32x2 cm[4];
    #pragma unroll
    for (int j = 0; j < 4; ++j) cm[j] = b[0][j];
    #pragma unroll
    for (int r = 1; r < 8; ++r)
      #pragma unroll
      for (int j = 0; j < 4; ++j) cm[j] = pkmax(cm[j], b[r][j]);
    float cmf[8] = {cm[0].x, cm[0].y, cm[1].x, cm[1].y,
                    cm[2].x, cm[2].y, cm[3].x, cm[3].y};
    #pragma unroll
    for (int k = 0; k < 8; ++k) cmf[k] = swap32_max(cmf[k]);
    if (tid & 32) {
      ldsT[wbase + 4] = cmf[4]; ldsT[wbase + 5] = cmf[5];
      ldsT[wbase + 6] = cmf[6]; ldsT[wbase + 7] = cmf[7];
    } else {
      ldsT[wbase + 0] = cmf[0]; ldsT[wbase + 1] = cmf[1];
      ldsT[wbase + 2] = cmf[2]; ldsT[wbase + 3] = cmf[3];
    }
  }
  __syncthreads();
  {
    const int col = tid >> 2, q4 = tid & 3;
    const int slot = (col >> 3) * 9 + (col & 7);
    float M = -3.0e38f;
    #pragma unroll
    for (int k = 0; k < 4; ++k) {
      int row = q4 * 4 + k;
      M = fmaxf(M, ldsT[row * TSTRIDE + slot + 4 * row]);
    }
    M = fmaxf(M, dppf<0xB1>(M));
    M = fmaxf(M, dppf<0x4E>(M));
    if (q4 == 0) ldsM[col] = M;
  }
  __syncthreads();

  // ---------- phase C: b = 2^(u-M-K); G_j = sum_i b*2^{K_i} -> C1 ----------
  {
    const float4* m4 = reinterpret_cast<const float4*>(ldsM);
    float4 mA = m4[cg * 2], mB = m4[cg * 2 + 1];
    f32x2 Mv[4] = {{mA.x, mA.y}, {mA.z, mA.w}, {mB.x, mB.y}, {mB.z, mB.w}};
    f32x2 cs[4];
    cs[0] = cs[1] = cs[2] = cs[3] = (f32x2){0.f, 0.f};
    #pragma unroll
    for (int r = 0; r < 8; ++r) {
      f32x2 v0 = b[r][0] - Mv[0], v1 = b[r][1] - Mv[1];
      f32x2 v2 = b[r][2] - Mv[2], v3 = b[r][3] - Mv[3];
      f32x2 km = pkmax(pkmax(v0, v1), pkmax(v2, v3));
      float K = rmax32(fmaxf(km.x, km.y));  // row max of (u - M), <= 0
      float eK = __builtin_amdgcn_exp2f(K);
      b[r][0].x = __builtin_amdgcn_exp2f(v0.x - K);
      b[r][0].y = __builtin_amdgcn_exp2f(v0.y - K);
      b[r][1].x = __builtin_amdgcn_exp2f(v1.x - K);
      b[r][1].y = __builtin_amdgcn_exp2f(v1.y - K);
      b[r][2].x = __builtin_amdgcn_exp2f(v2.x - K);
      b[r][2].y = __builtin_amdgcn_exp2f(v2.y - K);
      b[r][3].x = __builtin_amdgcn_exp2f(v3.x - K);
      b[r][3].y = __builtin_amdgcn_exp2f(v3.y - K);
      f32x2 eK2 = (f32x2){eK, eK};
      cs[0] += b[r][0] * eK2;
      cs[1] += b[r][1] * eK2;
      cs[2] += b[r][2] * eK2;
      cs[3] += b[r][3] * eK2;
    }
    float csf[8] = {cs[0].x, cs[0].y, cs[1].x, cs[1].y,
                    cs[2].x, cs[2].y, cs[3].x, cs[3].y};
    #pragma unroll
    for (int k = 0; k < 8; ++k) csf[k] = swap32_add(csf[k]);
    if (tid & 32) {
      ldsT[wbase + 4] = csf[4]; ldsT[wbase + 5] = csf[5];
      ldsT[wbase + 6] = csf[6]; ldsT[wbase + 7] = csf[7];
    } else {
      ldsT[wbase + 0] = csf[0]; ldsT[wbase + 1] = csf[1];
      ldsT[wbase + 2] = csf[2]; ldsT[wbase + 3] = csf[3];
    }
  }
  __syncthreads();
  {
    const int col = tid >> 2, q4 = tid & 3;
    const int slot = (col >> 3) * 9 + (col & 7);
    float S = 0.f;
    #pragma unroll
    for (int k = 0; k < 4; ++k) {
      int row = q4 * 4 + k;
      S += ldsT[row * TSTRIDE + slot + 4 * row];
    }
    S += dppf<0xB1>(S);
    S += dppf<0x4E>(S);
    if (q4 == 0) ldsCf[col] = __builtin_amdgcn_rcpf(fmaxf(S, 1e-30f));
  }
  __syncthreads();

  f32x2 Cv[4];
  {
    const float4* cf4 = reinterpret_cast<const float4*>(ldsCf);
    float4 cA = cf4[cg * 2], cB = cf4[cg * 2 + 1];
    Cv[0] = (f32x2){cA.x, cA.y}; Cv[1] = (f32x2){cA.z, cA.w};
    Cv[2] = (f32x2){cB.x, cB.y}; Cv[3] = (f32x2){cB.z, cB.w};
  }

  // ---------- iterations 2..20 (19x): packed-math R then C ----------
  #pragma unroll 1
  for (int it = 0; it < 19; ++it) {
    f32x2 ps[4];
    ps[0] = ps[1] = ps[2] = ps[3] = (f32x2){0.f, 0.f};
    #pragma unroll
    for (int r = 0; r < 8; ++r) {
      f32x2 s2 = b[r][0] * Cv[0];
      s2 += b[r][1] * Cv[1];
      s2 += b[r][2] * Cv[2];
      s2 += b[r][3] * Cv[3];
      float s = rsum32(s2.x + s2.y);
      float Rr = __builtin_amdgcn_rcpf(fmaxf(s, 1e-30f));
      f32x2 R2 = (f32x2){Rr, Rr};
      ps[0] += b[r][0] * R2;
      ps[1] += b[r][1] * R2;
      ps[2] += b[r][2] * R2;
      ps[3] += b[r][3] * R2;
    }
    float pf[8] = {ps[0].x, ps[0].y, ps[1].x, ps[1].y,
                   ps[2].x, ps[2].y, ps[3].x, ps[3].y};
    #pragma unroll
    for (int k = 0; k < 8; ++k) pf[k] = swap32_add(pf[k]);
    if (tid & 32) {
      ldsT[wbase + 4] = pf[4]; ldsT[wbase + 5] = pf[5];
      ldsT[wbase + 6] = pf[6]; ldsT[wbase + 7] = pf[7];
    } else {
      ldsT[wbase + 0] = pf[0]; ldsT[wbase + 1] = pf[1];
      ldsT[wbase + 2] = pf[2]; ldsT[wbase + 3] = pf[3];
    }
    __syncthreads();
    {
      const int col = tid >> 2, q4 = tid & 3;
      const int slot = (col >> 3) * 9 + (col & 7);
      float S = 0.f;
      #pragma unroll
      for (int k = 0; k < 4; ++k) {
        int row = q4 * 4 + k;
        S += ldsT[row * TSTRIDE + slot + 4 * row];
      }
      S += dppf<0xB1>(S);
      S += dppf<0x4E>(S);
      if (q4 == 0) ldsCf[col] = __builtin_amdgcn_rcpf(fmaxf(S, 1e-30f));
    }
    __syncthreads();
    {
      const float4* cf4 = reinterpret_cast<const float4*>(ldsCf);
      float4 cA = cf4[cg * 2], cB = cf4[cg * 2 + 1];
      Cv[0] = (f32x2){cA.x, cA.y}; Cv[1] = (f32x2){cA.z, cA.w};
      Cv[2] = (f32x2){cB.x, cB.y}; Cv[3] = (f32x2){cB.z, cB.w};
    }
  }

  // ---------- peeled iteration 21: keep R, final C ----------
  float R[8];
  {
    f32x2 ps[4];
    ps[0] = ps[1] = ps[2] = ps[3] = (f32x2){0.f, 0.f};
    #pragma unroll
    for (int r = 0; r < 8; ++r) {
      f32x2 s2 = b[r][0] * Cv[0];
      s2 += b[r][1] * Cv[1];
      s2 += b[r][2] * Cv[2];
      s2 += b[r][3] * Cv[3];
      float s = rsum32(s2.x + s2.y);
      float Rr = __builtin_amdgcn_rcpf(fmaxf(s, 1e-30f));
      R[r] = Rr;
      f32x2 R2 = (f32x2){Rr, Rr};
      ps[0] += b[r][0] * R2;
      ps[1] += b[r][1] * R2;
      ps[2] += b[r][2] * R2;
      ps[3] += b[r][3] * R2;
    }
    float pf[8] = {ps[0].x, ps[0].y, ps[1].x, ps[1].y,
                   ps[2].x, ps[2].y, ps[3].x, ps[3].y};
    #pragma unroll
    for (int k = 0; k < 8; ++k) pf[k] = swap32_add(pf[k]);
    if (tid & 32) {
      ldsT[wbase + 4] = pf[4]; ldsT[wbase + 5] = pf[5];
      ldsT[wbase + 6] = pf[6]; ldsT[wbase + 7] = pf[7];
    } else {
      ldsT[wbase + 0] = pf[0]; ldsT[wbase + 1] = pf[1];
      ldsT[wbase + 2] = pf[2]; ldsT[wbase + 3] = pf[3];
    }
    __syncthreads();
    {
      const int col = tid >> 2, q4 = tid & 3;
      const int slot = (col >> 3) * 9 + (col & 7);
      float S = 0.f;
      #pragma unroll
      for (int k = 0; k < 4; ++k) {
        int row = q4 * 4 + k;
        S += ldsT[row * TSTRIDE + slot + 4 * row];
      }
      S += dppf<0xB1>(S);
      S += dppf<0x4E>(S);
      if (q4 == 0) ldsCf[col] = __builtin_amdgcn_rcpf(fmaxf(S, 1e-30f));
    }
    __syncthreads();
  }

  // ---------- output: P = b * R_i * C_j ----------
  float4* __restrict__ dst4 =
      reinterpret_cast<float4*>(out + mat * (long)(N * N));
  const float4* cf4 = reinterpret_cast<const float4*>(ldsCf);
  float4 cA = cf4[cg * 2], cB = cf4[cg * 2 + 1];
  f32x2 C0 = (f32x2){cA.x, cA.y}, C1 = (f32x2){cA.z, cA.w};
  f32x2 C2 = (f32x2){cB.x, cB.y}, C3 = (f32x2){cB.z, cB.w};
  #pragma unroll
  for (int r = 0; r < 8; ++r) {
    f32x2 R2 = (f32x2){R[r], R[r]};
    f32x2 o0 = b[r][0] * R2 * C0;
    f32x2 o1 = b[r][1] * R2 * C1;
    f32x2 o2 = b[r][2] * R2 * C2;
    f32x2 o3 = b[r][3] * R2 * C3;
    dst4[(r0 + r) * 64 + cg * 2] = make_float4(o0.x, o0.y, o1.x, o1.y);
    dst4[(r0 + r) * 64 + cg * 2 + 1] = make_float4(o2.x, o2.y, o3.x, o3.y);
  }
}

extern "C" void kernel_launch(void* const* d_in, const int* in_sizes, int n_in,
                              void* d_out, int out_size, void* d_ws, size_t ws_size,
                              hipStream_t stream) {
  const float* x = (const float*)d_in[0];
  float* out = (float*)d_out;
  int B = in_sizes[0] / (N * N);
  hipLaunchKernelGGL(sinkhorn_kernel, dim3(B), dim3(BLK), 0, stream, x, out);
}